// Round 1
// baseline (1453.961 us; speedup 1.0000x reference)
//
#include <hip/hip_runtime.h>

#define B_  16
#define CI_ 32
#define H_  224
#define W_  224
#define CO_ 32
#define OH_ 222
#define OW_ 222

// Each thread: fixed (b, co, oh), 4 consecutive ow outputs.
// Per (ci, kh): one aligned float4 + 2 guarded scalar loads give the 6 input
// cols needed for 4 outputs x 3 kw taps (register sliding window).
// Weights are wave-uniform (co from blockIdx.z, ci/kh/kw are loop counters)
// -> scalar loads, broadcast free.
__global__ __launch_bounds__(256, 2) void conv2d_direct(
    const float* __restrict__ x, const float* __restrict__ w,
    const float* __restrict__ bias, float* __restrict__ out)
{
    const int tid = threadIdx.x;
    const int oh  = blockIdx.y * 4 + (tid >> 6);
    const int ow0 = (tid & 63) * 4;
    const int bc  = blockIdx.z;          // b * CO + co
    const int b   = bc >> 5;
    const int co  = bc & 31;
    if (oh >= OH_ || ow0 >= OW_) return;

    // Lanes with ow0 <= 218 may load cols ow0+4, ow0+5 (<= 223, in-row).
    // Lane ow0==220 only produces 2 valid outputs; its taps stay in the float4.
    const bool full = (ow0 + 5) < W_;

    float a0 = 0.f, a1 = 0.f, a2 = 0.f, a3 = 0.f;

    const float* xb = x + (size_t)b * CI_ * H_ * W_;
    const float* wc = w + (size_t)co * CI_ * 9;

    for (int ci = 0; ci < CI_; ++ci) {
        const float* xr = xb + (size_t)ci * H_ * W_ + (size_t)oh * W_ + ow0;
        const float* wp = wc + ci * 9;
#pragma unroll
        for (int kh = 0; kh < 3; ++kh) {
            const float* row = xr + kh * W_;
            // row start: base + 4*(ci*50176 + oh*224 + ow0), ow0 % 4 == 0,
            // 224 % 4 == 0 -> 16B aligned.
            const float4 v = *reinterpret_cast<const float4*>(row);
            const float x4 = full ? row[4] : 0.f;
            const float x5 = full ? row[5] : 0.f;

            const float w0 = wp[kh * 3 + 0];
            const float w1 = wp[kh * 3 + 1];
            const float w2 = wp[kh * 3 + 2];

            a0 += v.x * w0;  a1 += v.y * w0;  a2 += v.z * w0;  a3 += v.w * w0;
            a0 += v.y * w1;  a1 += v.z * w1;  a2 += v.w * w1;  a3 += x4  * w1;
            a0 += v.z * w2;  a1 += v.w * w2;  a2 += x4  * w2;  a3 += x5  * w2;
        }
    }

    const float bv = bias[co];
    const size_t o = ((size_t)(b * CO_ + co) * OH_ + oh) * OW_ + ow0;
    out[o + 0] = a0 + bv;
    out[o + 1] = a1 + bv;                 // ow0 <= 220 -> ow0+1 <= 221, valid
    if (ow0 + 2 < OW_) out[o + 2] = a2 + bv;
    if (ow0 + 3 < OW_) out[o + 3] = a3 + bv;
}

extern "C" void kernel_launch(void* const* d_in, const int* in_sizes, int n_in,
                              void* d_out, int out_size, void* d_ws, size_t ws_size,
                              hipStream_t stream) {
    const float* x    = (const float*)d_in[0];
    const float* w    = (const float*)d_in[1];
    const float* bias = (const float*)d_in[2];
    float* out        = (float*)d_out;

    dim3 block(256);
    dim3 grid(1, (OH_ + 3) / 4, B_ * CO_);   // 56 oh-quads, 16*32 (b,co) pairs
    conv2d_direct<<<grid, block, 0, stream>>>(x, w, bias, out);
}

// Round 2
// 327.777 us; speedup vs baseline: 4.4358x; 4.4358x over previous
//
#include <hip/hip_runtime.h>

#define B_  16
#define CI_ 32
#define H_  224
#define W_  224
#define CO_ 32
#define OH_ 222
#define OW_ 222
#define HW_ (H_*W_)   // 50176
#define K_  288       // CI_*9

#define XCOLS 66      // 64 outputs + 2 halo cols
#define CISTR 40      // padded ci stride in bf16 units: 80B, 16B-aligned, 2-way-free frag reads

typedef __attribute__((ext_vector_type(8))) short short8;   // 8 bf16 = 4 VGPRs
typedef __attribute__((ext_vector_type(4))) float float4v;  // MFMA C/D

__device__ __forceinline__ unsigned short f2bf(float f) {
    // round-to-nearest-even fp32 -> bf16 (inputs are finite normals)
    unsigned int u = __float_as_uint(f);
    u = u + 0x7FFFu + ((u >> 16) & 1u);
    return (unsigned short)(u >> 16);
}

// Permute+convert weights once per launch: ws[co*288 + (kh*3+kw)*32 + ci] = bf16(w[co][ci][kh][kw])
__global__ void wprep(const float* __restrict__ w, unsigned short* __restrict__ wbf) {
    int idx = blockIdx.x * 256 + threadIdx.x;
    if (idx >= CO_ * K_) return;
    int co  = idx / K_;
    int rem = idx - co * K_;
    int ci  = rem / 9;
    int g   = rem - ci * 9;           // kh*3+kw
    wbf[co * K_ + g * 32 + ci] = f2bf(w[idx]);
}

// Implicit GEMM: C[m=pixel][n=co] = sum_k X[m][k] * W[n][k]
// Block: 64 ow-pixels (4 waves x 16) x 32 co (2 n-tiles), one (b, oh).
// A-frag (X): lane m=lane&15, k=quad*8+j  -> ds_read_b128 from Xs[kh][col][ci]
// B-frag (W): lane n=lane&15, k=quad*8+j  -> global 16B load from wbf (L1/L2-hot)
// C/D: col(n=co)=lane&15, row(m=pixel)=quad*4+reg
__global__ __launch_bounds__(256) void conv_mfma(
    const float* __restrict__ x, const unsigned short* __restrict__ wbf,
    const float* __restrict__ bias, float* __restrict__ out)
{
    __shared__ unsigned short Xs[3 * XCOLS * CISTR];   // 15840 B

    const int t    = threadIdx.x;
    const int lane = t & 63;
    const int wv   = t >> 6;          // wave id = m-tile (16 pixels each)
    const int ow0  = blockIdx.x * 64;
    const int oh   = blockIdx.y;
    const int b    = blockIdx.z;

    // ---------- fill Xs[kh][col][ci] = bf16(x[b][ci][oh+kh][ow0+col]) ----------
    // thread t: col = t&63, ci-group = t>>6 (8 ci each); each wave's 64 lanes
    // read 64 consecutive cols -> coalesced 256B per load instr.
    {
        const int col = t & 63;
        const int ci0 = (t >> 6) * 8;
        const float* xb = x + (size_t)b * CI_ * HW_;
#pragma unroll
        for (int kh = 0; kh < 3; ++kh) {
            const float* base = xb + (size_t)(oh + kh) * W_ + ow0;
            // main cols 0..63
            {
                const bool v = (ow0 + col) < W_;
                short8 pk;
#pragma unroll
                for (int i = 0; i < 8; ++i) {
                    float f = v ? base[(size_t)(ci0 + i) * HW_ + col] : 0.0f;
                    pk[i] = (short)f2bf(f);
                }
                *(short8*)&Xs[(kh * XCOLS + col) * CISTR + ci0] = pk;
            }
            // halo cols 64,65
            if (col < 2) {
                const int c2 = 64 + col;
                const bool v = (ow0 + c2) < W_;
                short8 pk;
#pragma unroll
                for (int i = 0; i < 8; ++i) {
                    float f = v ? base[(size_t)(ci0 + i) * HW_ + c2] : 0.0f;
                    pk[i] = (short)f2bf(f);
                }
                *(short8*)&Xs[(kh * XCOLS + c2) * CISTR + ci0] = pk;
            }
        }
    }
    __syncthreads();

    // ---------- K-loop: 9 groups (kh,kw) x 32 ci ----------
    const int i16  = lane & 15;
    const int quad = lane >> 4;

    float4v acc0 = {0.f, 0.f, 0.f, 0.f};
    float4v acc1 = {0.f, 0.f, 0.f, 0.f};

    const unsigned short* wrow0 = wbf + (size_t)i16 * K_;          // co = i16
    const unsigned short* wrow1 = wbf + (size_t)(16 + i16) * K_;   // co = 16+i16

#pragma unroll
    for (int g = 0; g < 9; ++g) {
        const int kh = g / 3;
        const int kw = g - kh * 3;
        const short8 a  = *(const short8*)&Xs[(kh * XCOLS + wv * 16 + i16 + kw) * CISTR + quad * 8];
        const short8 b0 = *(const short8*)&wrow0[g * 32 + quad * 8];
        const short8 b1 = *(const short8*)&wrow1[g * 32 + quad * 8];
        acc0 = __builtin_amdgcn_mfma_f32_16x16x32_bf16(a, b0, acc0, 0, 0, 0);
        acc1 = __builtin_amdgcn_mfma_f32_16x16x32_bf16(a, b1, acc1, 0, 0, 0);
    }

    // ---------- epilogue: lane holds co=i16(+16), pixels ow0+wv*16+quad*4+r ----------
    const float bv0 = bias[i16];
    const float bv1 = bias[16 + i16];
    const int owbase = ow0 + wv * 16 + quad * 4;
    const size_t o0 = ((size_t)(b * CO_ + i16) * OH_ + oh) * (size_t)OW_;
    const size_t o1 = ((size_t)(b * CO_ + 16 + i16) * OH_ + oh) * (size_t)OW_;
#pragma unroll
    for (int r = 0; r < 4; ++r) {
        const int ow = owbase + r;
        if (ow < OW_) {
            out[o0 + ow] = acc0[r] + bv0;
            out[o1 + ow] = acc1[r] + bv1;
        }
    }
}

extern "C" void kernel_launch(void* const* d_in, const int* in_sizes, int n_in,
                              void* d_out, int out_size, void* d_ws, size_t ws_size,
                              hipStream_t stream) {
    const float* x    = (const float*)d_in[0];
    const float* w    = (const float*)d_in[1];
    const float* bias = (const float*)d_in[2];
    float* out        = (float*)d_out;
    unsigned short* wbf = (unsigned short*)d_ws;   // 9216 bf16 = 18432 B

    wprep<<<(CO_ * K_ + 255) / 256, 256, 0, stream>>>(w, wbf);

    dim3 grid((OW_ + 63) / 64, OH_, B_);           // 4 x 222 x 16 = 14208 blocks
    conv_mfma<<<grid, 256, 0, stream>>>(x, wbf, bias, out);
}